// Round 1
// baseline (1142.430 us; speedup 1.0000x reference)
//
#include <hip/hip_runtime.h>
#include <hip/hip_bf16.h>
#include <math.h>

// Problem constants
// B=2, C=64, H=W=128, SCALE=4 -> 512x512 hi-res, KUP=5 (25 taps), E=64
// d_out = [final | sapa | enc], each 2*64*512*512 floats

#define DEVFN static __device__ __forceinline__

DEVFN float keys_w(float d) {
    // Keys cubic a=-0.5 (jax.image 'cubic'), d >= 0
    if (d < 1.f) return ((1.5f * d - 2.5f) * d) * d + 1.f;
    if (d < 2.f) return ((-0.5f * d + 2.5f) * d - 4.f) * d + 2.f;
    return 0.f;
}

DEVFN void bicubic_axis(int o, int n, int idx4[4], float w4[4]) {
    // jax.image.resize semantics: sample = (o+0.5)/4 - 0.5; taps base-1..base+2,
    // out-of-range taps dropped, weights renormalized (NOT clamped).
    float f = (o + 0.5f) * 0.25f - 0.5f;
    float fb = floorf(f);
    int ib = (int)fb;
    float t = f - fb;
    float ws[4];
    ws[0] = keys_w(1.f + t);
    ws[1] = keys_w(t);
    ws[2] = keys_w(1.f - t);
    ws[3] = keys_w(2.f - t);
    float s = 0.f;
#pragma unroll
    for (int m = 0; m < 4; m++) {
        int ix = ib - 1 + m;
        if (ix < 0 || ix >= n) ws[m] = 0.f;
        s += ws[m];
        idx4[m] = min(max(ix, 0), n - 1);
    }
    float inv = 1.f / s;
#pragma unroll
    for (int m = 0; m < 4; m++) w4[m] = ws[m] * inv;
}

// ---------------- gate = sigmoid(conv1x1_64->64(bicubic_up(x))) -> bf16 ----------------
__global__ __launch_bounds__(256) void k_gate(const float* __restrict__ x,
                                              const float* __restrict__ gw,
                                              const float* __restrict__ gb,
                                              __hip_bfloat16* __restrict__ gate) {
    int idx = blockIdx.x * 256 + threadIdx.x;
    int j = idx & 511, i = (idx >> 9) & 511, b = idx >> 18;
    int iy[4], ix[4];
    float wy[4], wx[4];
    bicubic_axis(i, 128, iy, wy);
    bicubic_axis(j, 128, ix, wx);
    const float* xb = x + (size_t)b * 64 * 16384;
    float g[64];
#pragma unroll
    for (int oc = 0; oc < 64; oc++) g[oc] = gb[oc];
    for (int c = 0; c < 64; c++) {
        const float* xc = xb + c * 16384;
        float up = 0.f;
#pragma unroll
        for (int m = 0; m < 4; m++) {
            const float* row = xc + iy[m] * 128;
            float s = wx[0] * row[ix[0]] + wx[1] * row[ix[1]] + wx[2] * row[ix[2]] + wx[3] * row[ix[3]];
            up = fmaf(wy[m], s, up);
        }
#pragma unroll
        for (int oc = 0; oc < 64; oc++) g[oc] = fmaf(up, gw[oc * 64 + c], g[oc]);
    }
    size_t base = ((size_t)b << 24) + ((size_t)i << 9) + j;
#pragma unroll
    for (int oc = 0; oc < 64; oc++) {
        float s = 1.f / (1.f + expf(-g[oc]));
        gate[base + ((size_t)oc << 18)] = __float2bfloat16(s);
    }
}

// ---------------- f0 = conv1x1_67->16(concat(y, up_x)) ----------------
__global__ __launch_bounds__(256) void k_pc1a(const float* __restrict__ x,
                                              const float* __restrict__ y,
                                              const float* __restrict__ w,
                                              const float* __restrict__ bias,
                                              float* __restrict__ f0) {
    int idx = blockIdx.x * 256 + threadIdx.x;
    int j = idx & 511, i = (idx >> 9) & 511, b = idx >> 18;
    int iy[4], ix[4];
    float wy[4], wx[4];
    bicubic_axis(i, 128, iy, wy);
    bicubic_axis(j, 128, ix, wx);
    size_t hi = ((size_t)i << 9) + j;
    float acc[16];
#pragma unroll
    for (int oc = 0; oc < 16; oc++) acc[oc] = bias[oc];
    // y channels come first in the concat
#pragma unroll
    for (int cy = 0; cy < 3; cy++) {
        float v = y[((size_t)(b * 3 + cy) << 18) + hi];
#pragma unroll
        for (int oc = 0; oc < 16; oc++) acc[oc] = fmaf(v, w[oc * 67 + cy], acc[oc]);
    }
    const float* xb = x + (size_t)b * 64 * 16384;
    for (int c = 0; c < 64; c++) {
        const float* xc = xb + c * 16384;
        float up = 0.f;
#pragma unroll
        for (int m = 0; m < 4; m++) {
            const float* row = xc + iy[m] * 128;
            float s = wx[0] * row[ix[0]] + wx[1] * row[ix[1]] + wx[2] * row[ix[2]] + wx[3] * row[ix[3]];
            up = fmaf(wy[m], s, up);
        }
#pragma unroll
        for (int oc = 0; oc < 16; oc++) acc[oc] = fmaf(up, w[oc * 67 + 3 + c], acc[oc]);
    }
#pragma unroll
    for (int oc = 0; oc < 16; oc++) f0[((size_t)(b * 16 + oc) << 18) + hi] = acc[oc];
}

// ---------------- 5x5 conv 16->16 pad 2 ----------------
__global__ __launch_bounds__(256) void k_conv5(const float* __restrict__ fin,
                                               const float* __restrict__ w,
                                               const float* __restrict__ bias,
                                               float* __restrict__ fout) {
    int idx = blockIdx.x * 256 + threadIdx.x;
    int j = idx & 511, i = (idx >> 9) & 511, b = idx >> 18;
    const float* fb = fin + (size_t)b * 16 * 262144;
    float acc[16];
#pragma unroll
    for (int oc = 0; oc < 16; oc++) acc[oc] = bias[oc];
    for (int ky = 0; ky < 5; ky++) {
        int iy = i + ky - 2;
        if ((unsigned)iy >= 512u) continue;
        for (int kx = 0; kx < 5; kx++) {
            int jx = j + kx - 2;
            if ((unsigned)jx >= 512u) continue;
            size_t off = ((size_t)iy << 9) + jx;
#pragma unroll
            for (int ic = 0; ic < 16; ic++) {
                float v = fb[((size_t)ic << 18) + off];
#pragma unroll
                for (int oc = 0; oc < 16; oc++)
                    acc[oc] = fmaf(v, w[(oc * 16 + ic) * 25 + ky * 5 + kx], acc[oc]);
            }
        }
    }
    size_t hi = ((size_t)i << 9) + j;
#pragma unroll
    for (int oc = 0; oc < 16; oc++) fout[((size_t)(b * 16 + oc) << 18) + hi] = acc[oc];
}

// ---------------- 3x3 conv 16->16 pad 1 (optional relu) ----------------
template <bool RELU>
__global__ __launch_bounds__(256) void k_conv3(const float* __restrict__ fin,
                                               const float* __restrict__ w,
                                               const float* __restrict__ bias,
                                               float* __restrict__ fout) {
    int idx = blockIdx.x * 256 + threadIdx.x;
    int j = idx & 511, i = (idx >> 9) & 511, b = idx >> 18;
    const float* fb = fin + (size_t)b * 16 * 262144;
    float acc[16];
#pragma unroll
    for (int oc = 0; oc < 16; oc++) acc[oc] = bias[oc];
#pragma unroll
    for (int ky = 0; ky < 3; ky++) {
        int iy = i + ky - 1;
        if ((unsigned)iy >= 512u) continue;
#pragma unroll
        for (int kx = 0; kx < 3; kx++) {
            int jx = j + kx - 1;
            if ((unsigned)jx >= 512u) continue;
            size_t off = ((size_t)iy << 9) + jx;
#pragma unroll
            for (int ic = 0; ic < 16; ic++) {
                float v = fb[((size_t)ic << 18) + off];
#pragma unroll
                for (int oc = 0; oc < 16; oc++)
                    acc[oc] = fmaf(v, w[(oc * 16 + ic) * 9 + ky * 3 + kx], acc[oc]);
            }
        }
    }
    size_t hi = ((size_t)i << 9) + j;
#pragma unroll
    for (int oc = 0; oc < 16; oc++) {
        float v = acc[oc];
        if (RELU) v = fmaxf(v, 0.f);
        fout[((size_t)(b * 16 + oc) << 18) + hi] = v;
    }
}

// ---------------- spa2(t)+f1 residual, frq chain, cat -> f8 ----------------
__global__ __launch_bounds__(256) void k_tail(const float* __restrict__ f1,
                                              const float* __restrict__ t,
                                              const float* __restrict__ s2w, const float* __restrict__ s2b,
                                              const float* __restrict__ q1w, const float* __restrict__ q1b,
                                              const float* __restrict__ q2w, const float* __restrict__ q2b,
                                              const float* __restrict__ cw_, const float* __restrict__ cb_,
                                              float* __restrict__ f8) {
    int idx = blockIdx.x * 256 + threadIdx.x;
    int j = idx & 511, i = (idx >> 9) & 511, b = idx >> 18;
    size_t hi = ((size_t)i << 9) + j;
    const float* tb = t + (size_t)b * 16 * 262144;
    const float* fbp = f1 + (size_t)b * 16 * 262144;
    float sp[16];
#pragma unroll
    for (int oc = 0; oc < 16; oc++) sp[oc] = s2b[oc];
#pragma unroll
    for (int ky = 0; ky < 3; ky++) {
        int iy = i + ky - 1;
        if ((unsigned)iy >= 512u) continue;
#pragma unroll
        for (int kx = 0; kx < 3; kx++) {
            int jx = j + kx - 1;
            if ((unsigned)jx >= 512u) continue;
            size_t off = ((size_t)iy << 9) + jx;
#pragma unroll
            for (int ic = 0; ic < 16; ic++) {
                float v = tb[((size_t)ic << 18) + off];
#pragma unroll
                for (int oc = 0; oc < 16; oc++)
                    sp[oc] = fmaf(v, s2w[(oc * 16 + ic) * 9 + ky * 3 + kx], sp[oc]);
            }
        }
    }
    float fv[16];
#pragma unroll
    for (int c = 0; c < 16; c++) fv[c] = fbp[((size_t)c << 18) + hi];
#pragma unroll
    for (int c = 0; c < 16; c++) sp[c] += fv[c];  // residual
    float mid[16];
#pragma unroll
    for (int r = 0; r < 16; r++) {
        float m = q1b[r];
#pragma unroll
        for (int c = 0; c < 16; c++) m = fmaf(fv[c], q1w[r * 16 + c], m);
        mid[r] = fmaxf(m, 0.f);
    }
    float fo[16];
#pragma unroll
    for (int r = 0; r < 16; r++) {
        float m = q2b[r];
#pragma unroll
        for (int c = 0; c < 16; c++) m = fmaf(mid[c], q2w[r * 16 + c], m);
        fo[r] = m;
    }
#pragma unroll
    for (int o = 0; o < 8; o++) {
        float a = cb_[o];
#pragma unroll
        for (int c = 0; c < 16; c++) a = fmaf(sp[c], cw_[o * 32 + c], a);
#pragma unroll
        for (int c = 0; c < 16; c++) a = fmaf(fo[c], cw_[o * 32 + 16 + c], a);
        f8[((size_t)(b * 8 + o) << 18) + hi] = a;
    }
}

// ---------------- deterministic spatial mean reduction (partials) ----------------
__global__ __launch_bounds__(256) void k_pool(const float* __restrict__ f8, float* __restrict__ partials) {
    int bc = blockIdx.y;  // 0..15 = b*8+c
    const float* p = f8 + (size_t)bc * 262144;
    float s = 0.f;
    for (int tpos = blockIdx.x * 256 + threadIdx.x; tpos < 262144; tpos += 16 * 256) s += p[tpos];
#pragma unroll
    for (int off = 32; off; off >>= 1) s += __shfl_down(s, off, 64);
    __shared__ float ls[4];
    int lane = threadIdx.x & 63, wv = threadIdx.x >> 6;
    if (lane == 0) ls[wv] = s;
    __syncthreads();
    if (threadIdx.x == 0) partials[bc * 16 + blockIdx.x] = ls[0] + ls[1] + ls[2] + ls[3];
}

// ---------------- SE MLP: pooled -> channel weights ----------------
__global__ void k_se(const float* __restrict__ partials,
                     const float* __restrict__ w1, const float* __restrict__ b1,
                     const float* __restrict__ w2, const float* __restrict__ b2,
                     float* __restrict__ cw) {
    int b = threadIdx.x;
    if (b >= 2) return;
    float pooled[8];
#pragma unroll
    for (int c = 0; c < 8; c++) {
        float s = 0.f;
#pragma unroll
        for (int k = 0; k < 16; k++) s += partials[(b * 8 + c) * 16 + k];
        pooled[c] = s * (1.f / 262144.f);
    }
    float mid[2];
#pragma unroll
    for (int r = 0; r < 2; r++) {
        float m = b1[r];
#pragma unroll
        for (int c = 0; c < 8; c++) m = fmaf(w1[r * 8 + c], pooled[c], m);
        mid[r] = fmaxf(m, 0.f);
    }
#pragma unroll
    for (int c = 0; c < 8; c++) {
        float v = b2[c] + w2[c * 2 + 0] * mid[0] + w2[c * 2 + 1] * mid[1];
        cw[b * 8 + c] = 1.f / (1.f + expf(-v));
    }
}

// ---------------- enc = conv1x1_8->64(f8 * cw) ----------------
__global__ __launch_bounds__(256) void k_pc3(const float* __restrict__ f8, const float* __restrict__ cw,
                                             const float* __restrict__ w, const float* __restrict__ bias,
                                             float* __restrict__ enc) {
    int idx = blockIdx.x * 256 + threadIdx.x;
    int j = idx & 511, i = (idx >> 9) & 511, b = idx >> 18;
    size_t hi = ((size_t)i << 9) + j;
    float v[8];
#pragma unroll
    for (int c = 0; c < 8; c++) v[c] = f8[((size_t)(b * 8 + c) << 18) + hi] * cw[b * 8 + c];
#pragma unroll
    for (int oc = 0; oc < 64; oc++) {
        float a = bias[oc];
#pragma unroll
        for (int c = 0; c < 8; c++) a = fmaf(v[c], w[oc * 8 + c], a);
        enc[((size_t)(b * 64 + oc) << 18) + hi] = a;
    }
}

// ---------------- k-projection + transposed x at low res ----------------
__global__ __launch_bounds__(256) void k_kxb(const float* __restrict__ x,
                                             const float* __restrict__ g, const float* __restrict__ bb,
                                             const float* __restrict__ kw, const float* __restrict__ kbias,
                                             float* __restrict__ kb, float* __restrict__ xb) {
    int idx = blockIdx.x * 256 + threadIdx.x;  // 32768 = 2*128*128
    int w = idx & 127, h = (idx >> 7) & 127, b = idx >> 14;
    const float* xp = x + (size_t)b * 64 * 16384 + (h << 7) + w;
    float xv[64];
#pragma unroll
    for (int c = 0; c < 64; c++) xv[c] = xp[(size_t)c << 14];
    float4* xbp = (float4*)(xb + (size_t)idx * 64);
#pragma unroll
    for (int c4 = 0; c4 < 16; c4++)
        xbp[c4] = make_float4(xv[4 * c4], xv[4 * c4 + 1], xv[4 * c4 + 2], xv[4 * c4 + 3]);
    float m = 0.f;
#pragma unroll
    for (int c = 0; c < 64; c++) m += xv[c];
    m *= (1.f / 64.f);
    float var = 0.f;
#pragma unroll
    for (int c = 0; c < 64; c++) {
        float d = xv[c] - m;
        var = fmaf(d, d, var);
    }
    var *= (1.f / 64.f);
    float rstd = rsqrtf(var + 1e-5f);
#pragma unroll
    for (int c = 0; c < 64; c++) xv[c] = (xv[c] - m) * rstd * g[c] + bb[c];
    float* kp = kb + (size_t)idx * 64;
#pragma unroll
    for (int e = 0; e < 64; e++) {
        float s = kbias[e];
#pragma unroll
        for (int c = 0; c < 64; c++) s = fmaf(xv[c], kw[e * 64 + c], s);
        kp[e] = s;
    }
}

// ---------------- attention + final blend ----------------
__global__ __launch_bounds__(256) void k_attn(const float* __restrict__ enc,
                                              const __hip_bfloat16* __restrict__ gate,
                                              const float* __restrict__ kb, const float* __restrict__ xb,
                                              const float* __restrict__ lg, const float* __restrict__ lb,
                                              const float* __restrict__ qw, const float* __restrict__ qbias,
                                              float* __restrict__ sapa, float* __restrict__ fin) {
    int idx = blockIdx.x * 256 + threadIdx.x;
    int j = idx & 511, i = (idx >> 9) & 511, b = idx >> 18;
    int h = i >> 2, wq = j >> 2;
    size_t hi = ((size_t)i << 9) + j;
    const float* ep = enc + ((size_t)b << 24) + hi;
    float yn[64];
#pragma unroll
    for (int c = 0; c < 64; c++) yn[c] = ep[(size_t)c << 18];
    float m = 0.f;
#pragma unroll
    for (int c = 0; c < 64; c++) m += yn[c];
    m *= (1.f / 64.f);
    float var = 0.f;
#pragma unroll
    for (int c = 0; c < 64; c++) {
        float d = yn[c] - m;
        var = fmaf(d, d, var);
    }
    var *= (1.f / 64.f);
    float rstd = rsqrtf(var + 1e-5f);
#pragma unroll
    for (int c = 0; c < 64; c++) yn[c] = (yn[c] - m) * rstd * lg[c] + lb[c];
    float q[64];
#pragma unroll
    for (int e = 0; e < 64; e++) {
        float s = qbias[e];
#pragma unroll
        for (int c = 0; c < 64; c++) s = fmaf(yn[c], qw[e * 64 + c], s);
        q[e] = s;
    }
    // logits over 5x5 low-res neighborhood; OOB taps are exact 0 (zero-padded k)
    float a[25];
#pragma unroll
    for (int dy = -2; dy <= 2; dy++) {
#pragma unroll
        for (int dx = -2; dx <= 2; dx++) {
            int p = (dy + 2) * 5 + (dx + 2);
            int hh = h + dy, ww = wq + dx;
            float s = 0.f;
            if ((unsigned)hh < 128u && (unsigned)ww < 128u) {
                const float4* kp = (const float4*)(kb + (size_t)((b * 128 + hh) * 128 + ww) * 64);
#pragma unroll
                for (int e4 = 0; e4 < 16; e4++) {
                    float4 kv = kp[e4];
                    s = fmaf(q[4 * e4 + 0], kv.x, s);
                    s = fmaf(q[4 * e4 + 1], kv.y, s);
                    s = fmaf(q[4 * e4 + 2], kv.z, s);
                    s = fmaf(q[4 * e4 + 3], kv.w, s);
                }
            }
            a[p] = s;
        }
    }
    float mx = a[0];
#pragma unroll
    for (int p = 1; p < 25; p++) mx = fmaxf(mx, a[p]);
    float Z = 0.f;
#pragma unroll
    for (int p = 0; p < 25; p++) {
        a[p] = expf(a[p] - mx);
        Z += a[p];
    }
    float inv = 1.f / Z;
    float o[64];
#pragma unroll
    for (int c = 0; c < 64; c++) o[c] = 0.f;
#pragma unroll
    for (int dy = -2; dy <= 2; dy++) {
#pragma unroll
        for (int dx = -2; dx <= 2; dx++) {
            int p = (dy + 2) * 5 + (dx + 2);
            int hh = h + dy, ww = wq + dx;
            if ((unsigned)hh < 128u && (unsigned)ww < 128u) {
                float wp = a[p] * inv;
                const float4* xp = (const float4*)(xb + (size_t)((b * 128 + hh) * 128 + ww) * 64);
#pragma unroll
                for (int c4 = 0; c4 < 16; c4++) {
                    float4 xv = xp[c4];
                    o[4 * c4 + 0] = fmaf(wp, xv.x, o[4 * c4 + 0]);
                    o[4 * c4 + 1] = fmaf(wp, xv.y, o[4 * c4 + 1]);
                    o[4 * c4 + 2] = fmaf(wp, xv.z, o[4 * c4 + 2]);
                    o[4 * c4 + 3] = fmaf(wp, xv.w, o[4 * c4 + 3]);
                }
            }
        }
    }
#pragma unroll
    for (int c = 0; c < 64; c++) {
        size_t oidx = ((size_t)(b * 64 + c) << 18) + hi;
        float sv = o[c];
        sapa[oidx] = sv;
        float gv = __bfloat162float(gate[oidx]);
        float ev = ep[(size_t)c << 18];
        fin[oidx] = gv * sv + (1.f - gv) * ev;
    }
}

extern "C" void kernel_launch(void* const* d_in, const int* in_sizes, int n_in,
                              void* d_out, int out_size, void* d_ws, size_t ws_size,
                              hipStream_t stream) {
    const float* x = (const float*)d_in[0];
    const float* y = (const float*)d_in[1];
    const float* gate_w = (const float*)d_in[2];
    const float* gate_b = (const float*)d_in[3];
    const float* pc1a_w = (const float*)d_in[4];
    const float* pc1a_b = (const float*)d_in[5];
    const float* pc1b_w = (const float*)d_in[6];
    const float* pc1b_b = (const float*)d_in[7];
    const float* spa1_w = (const float*)d_in[8];
    const float* spa1_b = (const float*)d_in[9];
    const float* spa2_w = (const float*)d_in[10];
    const float* spa2_b = (const float*)d_in[11];
    const float* frq1_w = (const float*)d_in[12];
    const float* frq1_b = (const float*)d_in[13];
    const float* frq2_w = (const float*)d_in[14];
    const float* frq2_b = (const float*)d_in[15];
    const float* cat_w = (const float*)d_in[16];
    const float* cat_b = (const float*)d_in[17];
    const float* ca1_w = (const float*)d_in[18];
    const float* ca1_b = (const float*)d_in[19];
    const float* ca2_w = (const float*)d_in[20];
    const float* ca2_b = (const float*)d_in[21];
    const float* pc3_w = (const float*)d_in[22];
    const float* pc3_b = (const float*)d_in[23];
    const float* lny_g = (const float*)d_in[24];
    const float* lny_b = (const float*)d_in[25];
    const float* lnx_g = (const float*)d_in[26];
    const float* lnx_b = (const float*)d_in[27];
    const float* q_w = (const float*)d_in[28];
    const float* q_b = (const float*)d_in[29];
    const float* k_w = (const float*)d_in[30];
    const float* k_b = (const float*)d_in[31];

    float* out = (float*)d_out;
    float* finalp = out;                // (2,64,512,512)
    float* sapap = out + 33554432;      // (2,64,512,512)
    float* encp = out + 67108864;       // (2,64,512,512)

    char* ws = (char*)d_ws;
    __hip_bfloat16* gate = (__hip_bfloat16*)ws;   // 67,108,864 B
    float* f0 = (float*)(ws + 67108864);          // 33,554,432 B
    float* f1 = (float*)(ws + 100663296);         // 33,554,432 B
    float* f8 = (float*)(ws + 134217728);         // 16,777,216 B
    float* kbuf = (float*)(ws + 150994944);       // 8,388,608 B
    float* xbuf = (float*)(ws + 159383552);       // 8,388,608 B
    float* partials = (float*)(ws + 167772160);   // 1,024 B
    float* cw = (float*)(ws + 167773184);         // 64 B
    float* tbuf = f0;                              // reuse f0 after conv5 consumed it

    dim3 blk(256);
    dim3 gridHi(2048);  // 2*512*512/256

    k_gate<<<gridHi, blk, 0, stream>>>(x, gate_w, gate_b, gate);
    k_pc1a<<<gridHi, blk, 0, stream>>>(x, y, pc1a_w, pc1a_b, f0);
    k_conv5<<<gridHi, blk, 0, stream>>>(f0, pc1b_w, pc1b_b, f1);
    k_conv3<true><<<gridHi, blk, 0, stream>>>(f1, spa1_w, spa1_b, tbuf);
    k_tail<<<gridHi, blk, 0, stream>>>(f1, tbuf, spa2_w, spa2_b, frq1_w, frq1_b,
                                       frq2_w, frq2_b, cat_w, cat_b, f8);
    k_pool<<<dim3(16, 16), blk, 0, stream>>>(f8, partials);
    k_se<<<dim3(1), dim3(64), 0, stream>>>(partials, ca1_w, ca1_b, ca2_w, ca2_b, cw);
    k_pc3<<<gridHi, blk, 0, stream>>>(f8, cw, pc3_w, pc3_b, encp);
    k_kxb<<<dim3(128), blk, 0, stream>>>(x, lnx_g, lnx_b, k_w, k_b, kbuf, xbuf);
    k_attn<<<gridHi, blk, 0, stream>>>(encp, gate, kbuf, xbuf, lny_g, lny_b, q_w, q_b, sapap, finalp);
}